// Round 16
// baseline (372.080 us; speedup 1.0000x reference)
//
#include <hip/hip_runtime.h>
#include <hip/hip_bf16.h>

#define BS 8
#define V0 2048
#define V1N 512
#define V2N 128

typedef unsigned short ushort_t;
typedef __attribute__((ext_vector_type(8))) short bf16x8;
typedef __attribute__((ext_vector_type(4))) float f32x4;

// ---------------------------------------------------------------------------
// Threefry2x32 cipher (JAX partitionable mode — verified R4)
// ---------------------------------------------------------------------------
__device__ __forceinline__ void tf2x32(unsigned k0, unsigned k1,
                                       unsigned x0, unsigned x1,
                                       unsigned &o0, unsigned &o1) {
  unsigned ks2 = k0 ^ k1 ^ 0x1BD11BDAu;
  x0 += k0; x1 += k1;
#define RR(r) { x0 += x1; x1 = (x1 << (r)) | (x1 >> (32 - (r))); x1 ^= x0; }
  RR(13) RR(15) RR(26) RR(6)   x0 += k1;  x1 += ks2 + 1u;
  RR(17) RR(29) RR(16) RR(24)  x0 += ks2; x1 += k0 + 2u;
  RR(13) RR(15) RR(26) RR(6)   x0 += k0;  x1 += k1 + 3u;
  RR(17) RR(29) RR(16) RR(24)  x0 += k1;  x1 += ks2 + 4u;
  RR(13) RR(15) RR(26) RR(6)   x0 += ks2; x1 += k0 + 5u;
#undef RR
  o0 = x0; o1 = x1;
}

__device__ __forceinline__ ushort_t f2bf(float f) {
  unsigned u = __float_as_uint(f);
  u += 0x7FFFu + ((u >> 16) & 1u);
  return (ushort_t)(u >> 16);
}

__device__ __forceinline__ float sqdist_f32(float cx, float cy, float cz,
                                            const float* p) {
  float dx = __fsub_rn(cx, p[0]);
  float dy = __fsub_rn(cy, p[1]);
  float dz = __fsub_rn(cz, p[2]);
  return __fadd_rn(__fadd_rn(__fmul_rn(dx, dx), __fmul_rn(dy, dy)),
                   __fmul_rn(dz, dz));
}

#define KP1 1472   // 1424 real + zero pad to 64-multiple (BK=64)

// ---------------------------------------------------------------------------
// misc1: [0,PREP_BLKS) vectorized weight prep · then qbp lvl-1 (LDS-staged).
// ---------------------------------------------------------------------------
#define PREP_BLKS 1025   // 262,160 8-elem chunks / 256
#define QBP1_BLKS 512    // 16384 queries / 32
__global__ __launch_bounds__(256) void misc1_kernel(
    const float* __restrict__ cw1, const float* __restrict__ cw2,
    const float* __restrict__ cw3, const float* __restrict__ cb3,
    ushort_t* __restrict__ cw1b, ushort_t* __restrict__ cw2b,
    ushort_t* __restrict__ cw3b, float* __restrict__ cb3p,
    const float* __restrict__ pts, int* __restrict__ ni1) {
  int bid = blockIdx.x, tid = threadIdx.x;
  if (bid < PREP_BLKS) {
    int c = bid * 256 + tid;
    const int C1 = 1024 * (KP1 / 8);          // 188416
    const int C2 = (512 * 1024) / 8;          // 65536
    const int C3 = (128 * 512) / 8;           // 8192
    if (c < C1) {
      int n = c / (KP1 / 8);
      int cc = c - n * (KP1 / 8);
      int k = cc * 8;
      bf16x8 o = (bf16x8){0, 0, 0, 0, 0, 0, 0, 0};
      if (k < 1424) {                        // 1424 % 8 == 0: fully real
        const float* src = cw1 + (size_t)n * 1424 + k;
        float4 lo = *(const float4*)src;
        float4 hi = *(const float4*)(src + 4);
        o[0] = (short)f2bf(lo.x); o[1] = (short)f2bf(lo.y);
        o[2] = (short)f2bf(lo.z); o[3] = (short)f2bf(lo.w);
        o[4] = (short)f2bf(hi.x); o[5] = (short)f2bf(hi.y);
        o[6] = (short)f2bf(hi.z); o[7] = (short)f2bf(hi.w);
      }
      *(bf16x8*)(cw1b + (size_t)c * 8) = o;
    } else if (c < C1 + C2) {
      int u = (c - C1) * 8;
      const float* src = cw2 + u;
      float4 lo = *(const float4*)src;
      float4 hi = *(const float4*)(src + 4);
      bf16x8 o;
      o[0] = (short)f2bf(lo.x); o[1] = (short)f2bf(lo.y);
      o[2] = (short)f2bf(lo.z); o[3] = (short)f2bf(lo.w);
      o[4] = (short)f2bf(hi.x); o[5] = (short)f2bf(hi.y);
      o[6] = (short)f2bf(hi.z); o[7] = (short)f2bf(hi.w);
      *(bf16x8*)(cw2b + u) = o;
    } else if (c < C1 + C2 + C3) {
      int u = (c - C1 - C2) * 8;
      int n = u >> 9, k = u & 511;
      bf16x8 o = (bf16x8){0, 0, 0, 0, 0, 0, 0, 0};
      if (n < 50) {
        const float* src = cw3 + (size_t)n * 512 + k;
        float4 lo = *(const float4*)src;
        float4 hi = *(const float4*)(src + 4);
        o[0] = (short)f2bf(lo.x); o[1] = (short)f2bf(lo.y);
        o[2] = (short)f2bf(lo.z); o[3] = (short)f2bf(lo.w);
        o[4] = (short)f2bf(hi.x); o[5] = (short)f2bf(hi.y);
        o[6] = (short)f2bf(hi.z); o[7] = (short)f2bf(hi.w);
      }
      *(bf16x8*)(cw3b + u) = o;
    } else if (c < C1 + C2 + C3 + 16) {
      int u = (c - C1 - C2 - C3) * 8;
#pragma unroll
      for (int e = 0; e < 8; ++e)
        cb3p[u + e] = (u + e) < 50 ? cb3[u + e] : 0.f;
    }
  } else {
    // qbp level-1: stage batch's 2048 pts into LDS once, serve 32 queries.
    __shared__ float spts[V0 * 3];   // 24 KiB
    int bq = bid - PREP_BLKS;        // 0..511
    int qbase = bq * 32;             // 64 blocks per batch (2048 % 32 == 0)
    int b = qbase >> 11;
    const float* base = pts + (size_t)b * V0 * 3;
    for (int i = tid; i < V0 * 3 / 4; i += 256)
      ((float4*)spts)[i] = ((const float4*)base)[i];
    __syncthreads();
    int lane = tid & 63, wv = tid >> 6;
    for (int rep = 0; rep < 8; ++rep) {
      int qoff = wv * 8 + rep;
      int qi = (qbase & 2047) + qoff;
      int wid = qbase + qoff;
      float cx = spts[qi * 3], cy = spts[qi * 3 + 1], cz = spts[qi * 3 + 2];
      int cnt = 0, idx0 = 0;
      for (int j0 = 0; j0 < V0; j0 += 64) {
        int j = j0 + lane;
        float d2 = sqdist_f32(cx, cy, cz, spts + (size_t)j * 3);
        bool in = (d2 <= 0.0625f);
        unsigned long long mask = __ballot(in);
        if (cnt == 0 && mask) idx0 = j0 + __builtin_ctzll(mask);
        if (in) {
          int rk = cnt + __popcll(mask & ((1ull << lane) - 1ull));
          if (rk < 32) ni1[(size_t)wid * 32 + rk] = j;
        }
        cnt += __popcll(mask);
        if (cnt >= 32) break;
      }
      for (int s = cnt + lane; s < 32; s += 64) ni1[(size_t)wid * 32 + s] = idx0;
    }
  }
}

// ---------------------------------------------------------------------------
__device__ __forceinline__ void dirn(const float* base, int v, int nb,
                                     float& ox, float& oy, float& oz) {
  float dx = __fsub_rn(base[nb * 3 + 0], base[v * 3 + 0]);
  float dy = __fsub_rn(base[nb * 3 + 1], base[v * 3 + 1]);
  float dz = __fsub_rn(base[nb * 3 + 2], base[v * 3 + 2]);
  float s2 = __fadd_rn(__fadd_rn(__fmul_rn(dx, dx), __fmul_rn(dy, dy)),
                       __fmul_rn(dz, dz));
  float nrm = fmaxf(__fsqrt_rn(s2), 1e-12f);
  ox = __fdiv_rn(dx, nrm); oy = __fdiv_rn(dy, nrm); oz = __fdiv_rn(dz, nrm);
}

__device__ __forceinline__ void norm_col(const float* d, int k,
                                         float& ox, float& oy, float& oz) {
  float x = d[k], y = d[32 + k], z = d[64 + k];
  float s2 = __fadd_rn(__fadd_rn(__fmul_rn(x, x), __fmul_rn(y, y)),
                       __fmul_rn(z, z));
  float nrm = fmaxf(__fsqrt_rn(s2), 1e-12f);
  ox = __fdiv_rn(x, nrm); oy = __fdiv_rn(y, nrm); oz = __fdiv_rn(z, nrm);
}

// ---------------------------------------------------------------------------
// misc2: blocks [0,RANK_BLKS) = scan-split threefry rank (R15-verified:
// partial counts atomicAdd'd, hidden under conv_surface);
// blocks [RANK_BLKS, +2048) = conv_surface (+linear1).
// ---------------------------------------------------------------------------
#define RANK_PARTS 16
#define RANK_BLKS (18 * RANK_PARTS)
__global__ __launch_bounds__(256) void misc2_kernel(
    int* __restrict__ rank, const float* __restrict__ pts,
    const int* __restrict__ ni, const float* __restrict__ d0,
    const float* __restrict__ w1, const float* __restrict__ b1,
    float* __restrict__ out, float* __restrict__ fn) {
  int bid = blockIdx.x, tid = threadIdx.x;
  if (bid < RANK_BLKS) {
    __shared__ unsigned sb[128];
    int rid = bid >> 4, part = bid & (RANK_PARTS - 1);
    int seg, segfirst, n, base;
    if (rid < 8)       { seg = 0; segfirst = 0;  n = 2048; base = 0; }
    else if (rid < 16) { seg = 1; segfirst = 8;  n = 2048; base = 2048; }
    else               { seg = 2; segfirst = 16; n = 512;  base = 4096; }
    unsigned k0, k1, nk0, nk1, sk0, sk1;
    if (seg == 0) {
      tf2x32(0u, 42u, 0u, 1u, k0, k1);
      tf2x32(k0, k1, 0u, 1u, sk0, sk1);
    } else if (seg == 1) {
      tf2x32(0u, 42u, 0u, 1u, k0, k1);
      tf2x32(k0, k1, 0u, 0u, nk0, nk1);
      tf2x32(nk0, nk1, 0u, 1u, sk0, sk1);
    } else {
      tf2x32(0u, 42u, 0u, 2u, k0, k1);
      tf2x32(k0, k1, 0u, 1u, sk0, sk1);
    }
    int chunk = n / RANK_PARTS;        // 128 (n=2048) or 32 (n=512)
    int s0 = part * chunk;
    for (int i = tid; i < chunk; i += 256) {
      unsigned o0, o1;
      tf2x32(sk0, sk1, 0u, (unsigned)(s0 + i), o0, o1);
      sb[i] = o0 ^ o1;
    }
    __syncthreads();
    int tt = (rid - segfirst) * 256 + tid;
    unsigned o0, o1;
    tf2x32(sk0, sk1, 0u, (unsigned)tt, o0, o1);
    unsigned bt = o0 ^ o1;
    int cnt = 0;
#pragma unroll 8
    for (int j = 0; j < chunk; ++j) {
      unsigned bs = sb[j];
      cnt += (bs < bt) || (bs == bt && (s0 + j) < tt);
    }
    atomicAdd(&rank[base + tt], cnt);
    return;
  }
  __shared__ float sdir[3][32];
  __shared__ float sdn[8][32][3];
  __shared__ float sfm[8][32];
  if (tid < 32) {
    float x, y, z; norm_col(d0, tid, x, y, z);
    sdir[0][tid] = x; sdir[1][tid] = y; sdir[2][tid] = z;
  }
  int vloc = tid >> 5, k = tid & 31;
  size_t bvg = (size_t)(bid - RANK_BLKS) * 8 + vloc;
  int b = (int)(bvg >> 11), v = (int)(bvg & 2047);
  const float* base = pts + (size_t)b * V0 * 3;
  int nb = ni[bvg * 32 + k];
  float x, y, z; dirn(base, v, nb, x, y, z);
  sdn[vloc][k][0] = x; sdn[vloc][k][1] = y; sdn[vloc][k][2] = z;
  __syncthreads();
  float m = 0.f;
  for (int n = 0; n < 32; ++n) {
    float d = sdn[vloc][n][0] * sdir[0][k] + sdn[vloc][n][1] * sdir[1][k] +
              sdn[vloc][n][2] * sdir[2][k];
    m = fmaxf(m, fmaxf(d, 0.f));
  }
  out[bvg * 96 + k] = m;
  sfm[vloc][k] = m;
  __syncthreads();
  float a1v = b1[k], a2v = b1[k + 32];
  for (int c = 0; c < 32; ++c) {
    float vv = sfm[vloc][c];
    a1v += vv * w1[c * 64 + k];
    a2v += vv * w1[c * 64 + k + 32];
  }
  fn[bvg * 64 + k] = a1v;
  fn[bvg * 64 + k + 32] = a2v;
}

// ---------------------------------------------------------------------------
// perm_kernel: compose permutations from rank.
// ---------------------------------------------------------------------------
__global__ __launch_bounds__(256) void perm_kernel(
    const int* __restrict__ rank, int* __restrict__ perm1,
    int* __restrict__ perm2) {
  int tid = threadIdx.x;
  __shared__ int a1[2048];
  __shared__ int a2[2048];
  for (int i = tid; i < 2048; i += 256) a1[rank[i]] = i;
  __syncthreads();
  for (int i = tid; i < 2048; i += 256) a2[rank[2048 + i]] = a1[i];
  __syncthreads();
  for (int i = tid; i < 512; i += 256) perm1[i] = a2[i];
  for (int i = tid; i < 512; i += 256) a1[rank[4096 + i]] = i;
  __syncthreads();
  for (int i = tid; i < 128; i += 256) perm2[i] = a1[i];
}

// ---------------------------------------------------------------------------
// conv_act (+ optional fused next-linear)
// ---------------------------------------------------------------------------
__global__ __launch_bounds__(256) void conv_act_kernel(
    const float* __restrict__ pts, const float* __restrict__ dd,
    const int* __restrict__ ni, const float* __restrict__ f,
    float* __restrict__ out, int Nv, int ldout, int colofs,
    const float* __restrict__ wn, const float* __restrict__ bn,
    float* __restrict__ fn) {
  __shared__ float sdir[3][32];
  __shared__ float sdn[8][32][3];
  __shared__ int sidx[8][32];
  __shared__ float sfm[8][256];
  int tid = threadIdx.x;
  if (tid < 32) {
    float x, y, z; norm_col(dd, tid, x, y, z);
    sdir[0][tid] = x; sdir[1][tid] = y; sdir[2][tid] = z;
  }
  int vloc = tid >> 5, k = tid & 31;
  size_t bvg = (size_t)blockIdx.x * 8 + vloc;
  int b = (int)(bvg / Nv), v = (int)(bvg % Nv);
  const float* base = pts + (size_t)b * Nv * 3;
  int nb = ni[bvg * 32 + k];
  float x, y, z; dirn(base, v, nb, x, y, z);
  sdn[vloc][k][0] = x; sdn[vloc][k][1] = y; sdn[vloc][k][2] = z;
  sidx[vloc][k] = nb;
  __syncthreads();
  float m = -INFINITY;
  size_t fb = (size_t)b * Nv * 64;
  for (int n = 0; n < 32; ++n) {
    float th = fmaxf(sdn[vloc][n][0] * sdir[0][k] + sdn[vloc][n][1] * sdir[1][k] +
                     sdn[vloc][n][2] * sdir[2][k], 0.f);
    float sup = f[fb + (size_t)sidx[vloc][n] * 64 + 32 + k];
    m = fmaxf(m, th * sup);
  }
  float center = f[bvg * 64 + k];
  float res = fmaxf(center + m, 0.f);
  out[bvg * ldout + colofs + k] = res;
  if (wn) {
    size_t rowbase = (size_t)blockIdx.x * 8;
#pragma unroll 1
    for (int r = 0; r < 8; ++r)
      if (tid < colofs) sfm[r][tid] = out[(rowbase + r) * ldout + tid];
    sfm[vloc][colofs + k] = res;
    __syncthreads();
    int cin = colofs + 32;
    float a1v = bn[k], a2v = bn[k + 32];
    for (int c = 0; c < cin; ++c) {
      float vv = sfm[vloc][c];
      a1v += vv * wn[c * 64 + k];
      a2v += vv * wn[c * 64 + k + 32];
    }
    fn[bvg * 64 + k] = a1v;
    fn[bvg * 64 + k + 32] = a2v;
  }
}

// ---------------------------------------------------------------------------
// conv_act_qbp: qbp fused in front of conv_act (+fused linear)
// ---------------------------------------------------------------------------
__global__ __launch_bounds__(256) void conv_act_qbp_kernel(
    const float* __restrict__ pts, int Nv, float rrq,
    const float* __restrict__ dd, int* __restrict__ ni_out,
    const float* __restrict__ f, float* __restrict__ out, int ldout,
    int colofs, const float* __restrict__ wn, const float* __restrict__ bn,
    float* __restrict__ fn) {
  __shared__ float spts[512 * 3];
  __shared__ float sdir[3][32];
  __shared__ float sdn[8][32][3];
  __shared__ int sni[8][32];
  __shared__ float sfm[8][256];
  int tid = threadIdx.x;
  int b = (blockIdx.x * 8) / Nv;
  int vbase = (blockIdx.x * 8) % Nv;
  const float* gp = pts + (size_t)b * Nv * 3;
  for (int i = tid; i < Nv * 3; i += 256) spts[i] = gp[i];
  if (tid < 32) {
    float x, y, z; norm_col(dd, tid, x, y, z);
    sdir[0][tid] = x; sdir[1][tid] = y; sdir[2][tid] = z;
  }
  __syncthreads();
  int lane = tid & 63, wv = tid >> 6;
  for (int rep = 0; rep < 2; ++rep) {
    int vl = wv * 2 + rep;
    int v = vbase + vl;
    float cx = spts[v * 3], cy = spts[v * 3 + 1], cz = spts[v * 3 + 2];
    int cnt = 0, idx0 = 0;
    for (int j0 = 0; j0 < Nv; j0 += 64) {
      int j = j0 + lane;
      float d2 = sqdist_f32(cx, cy, cz, spts + (size_t)j * 3);
      bool in = (d2 <= rrq);
      unsigned long long mask = __ballot(in);
      if (cnt == 0 && mask) idx0 = j0 + __builtin_ctzll(mask);
      if (in) {
        int rk = cnt + __popcll(mask & ((1ull << lane) - 1ull));
        if (rk < 32) sni[vl][rk] = j;
      }
      cnt += __popcll(mask);
      if (cnt >= 32) break;
    }
    for (int s = cnt + lane; s < 32; s += 64) sni[vl][s] = idx0;
  }
  __syncthreads();
  ni_out[(size_t)(blockIdx.x * 8) * 32 + tid] = sni[tid >> 5][tid & 31];
  int vloc = tid >> 5, k = tid & 31;
  size_t bvg = (size_t)blockIdx.x * 8 + vloc;
  int v = vbase + vloc;
  int nb = sni[vloc][k];
  float x, y, z; dirn(spts, v, nb, x, y, z);
  sdn[vloc][k][0] = x; sdn[vloc][k][1] = y; sdn[vloc][k][2] = z;
  __syncthreads();
  float m = -INFINITY;
  size_t fb = (size_t)b * Nv * 64;
  for (int n = 0; n < 32; ++n) {
    float th = fmaxf(sdn[vloc][n][0] * sdir[0][k] + sdn[vloc][n][1] * sdir[1][k] +
                     sdn[vloc][n][2] * sdir[2][k], 0.f);
    float sup = f[fb + (size_t)sni[vloc][n] * 64 + 32 + k];
    m = fmaxf(m, th * sup);
  }
  float center = f[bvg * 64 + k];
  float res = fmaxf(center + m, 0.f);
  out[bvg * ldout + colofs + k] = res;
  size_t rowbase = (size_t)blockIdx.x * 8;
#pragma unroll 1
  for (int r = 0; r < 8; ++r)
    if (tid < colofs) sfm[r][tid] = out[(rowbase + r) * ldout + tid];
  sfm[vloc][colofs + k] = res;
  __syncthreads();
  int cin = colofs + 32;
  float a1v = bn[k], a2v = bn[k + 32];
  for (int c = 0; c < cin; ++c) {
    float vv = sfm[vloc][c];
    a1v += vv * wn[c * 64 + k];
    a2v += vv * wn[c * 64 + k + 32];
  }
  fn[bvg * 64 + k] = a1v;
  fn[bvg * 64 + k + 32] = a2v;
}

// ---------------------------------------------------------------------------
// pool (+ fused next-linear)
// ---------------------------------------------------------------------------
__global__ __launch_bounds__(256) void pool_kernel(
    const float* __restrict__ pts_in, const float* __restrict__ fm_in,
    int ld_in, int C, int Nv_in, const int* __restrict__ perm, int Nv_out,
    float rr, float* __restrict__ pts_out, float* __restrict__ fm_out,
    int ld_out, const float* __restrict__ wn, const float* __restrict__ bn,
    float* __restrict__ fn) {
  __shared__ float spf[4][192];
  int wv = threadIdx.x >> 6;
  int lane = threadIdx.x & 63;
  int wid = blockIdx.x * 4 + wv;
  int b = wid / Nv_out, pp = wid - b * Nv_out;
  int v = perm[pp];
  const float* base = pts_in + (size_t)b * Nv_in * 3;
  float cx = base[v * 3], cy = base[v * 3 + 1], cz = base[v * 3 + 2];
  int nb[4]; int cnt = 0;
  for (int j0 = 0; j0 < Nv_in && cnt < 4; j0 += 64) {
    int j = j0 + lane;
    float d2 = sqdist_f32(cx, cy, cz, base + (size_t)j * 3);
    unsigned long long mask = __ballot(d2 <= rr);
    while (mask && cnt < 4) {
      int bp = __builtin_ctzll(mask);
      mask &= mask - 1;
      nb[cnt++] = j0 + bp;
    }
  }
  for (int q = cnt; q < 4; ++q) nb[q] = nb[0];
  if (lane < 3) pts_out[(size_t)wid * 3 + lane] = base[v * 3 + lane];
  size_t inrow = (size_t)b * Nv_in;
  size_t outrow = (size_t)wid * ld_out;
  for (int c = lane; c < C; c += 64) {
    float m = fm_in[(inrow + nb[0]) * ld_in + c];
    m = fmaxf(m, fm_in[(inrow + nb[1]) * ld_in + c]);
    m = fmaxf(m, fm_in[(inrow + nb[2]) * ld_in + c]);
    m = fmaxf(m, fm_in[(inrow + nb[3]) * ld_in + c]);
    fm_out[outrow + c] = m;
    spf[wv][c] = m;
  }
  __syncthreads();
  int o = threadIdx.x & 63, w_ = threadIdx.x >> 6;
  int wid0 = blockIdx.x * 4 + w_;
  float a = bn[o];
  for (int c = 0; c < C; ++c) a += spf[w_][c] * wn[c * 64 + o];
  fn[(size_t)wid0 * 64 + o] = a;
}

// ---------------------------------------------------------------------------
// gmax: grid 64 = 8 batches × 8 col-groups; 256 thr = 8 v-sub × 32 cols.
// ---------------------------------------------------------------------------
__global__ __launch_bounds__(256) void gmax_kernel(
    const float* __restrict__ fm, float* __restrict__ out) {
  __shared__ float red[8][32];
  int b = blockIdx.x >> 3, cg = blockIdx.x & 7;
  int vsub = threadIdx.x >> 5, cl = threadIdx.x & 31;
  int c = cg * 32 + cl;
  float m = -INFINITY;
  for (int v = vsub; v < V2N; v += 8)
    m = fmaxf(m, fm[((size_t)b * V2N + v) * 256 + c]);
  red[vsub][cl] = m;
  __syncthreads();
  if (vsub == 0) {
#pragma unroll
    for (int r = 1; r < 8; ++r) m = fmaxf(m, red[r][cl]);
    out[b * 256 + c] = m;
  }
}

// ---------------------------------------------------------------------------
// fuse_row: wave-level shuffle argmin + gather (R7/R8 verified)
// ---------------------------------------------------------------------------
__global__ __launch_bounds__(256) void fuse_row_kernel(
    const float* __restrict__ fm2, const float* __restrict__ fm5,
    const float* __restrict__ fm7, const float* __restrict__ fglob,
    const float* __restrict__ onehot, const float* __restrict__ verts,
    const float* __restrict__ v1, const float* __restrict__ v2,
    ushort_t* __restrict__ fuse_b) {
  __shared__ unsigned long long sred[8];   // [0..3]=v1 per-wave, [4..7]=v2
  __shared__ int sn12[2];
  int bv = blockIdx.x;
  int b = bv >> 11;
  int tid = threadIdx.x;
  int lane = tid & 63, wv = tid >> 6;
  float cx = verts[(size_t)bv * 3 + 0];
  float cy = verts[(size_t)bv * 3 + 1];
  float cz = verts[(size_t)bv * 3 + 2];
  unsigned long long b1 = ~0ull, b2 = ~0ull;
  const float* s1 = v1 + (size_t)b * V1N * 3;
  for (int j = tid; j < V1N; j += 256) {
    float d2 = sqdist_f32(cx, cy, cz, s1 + (size_t)j * 3);
    unsigned long long key =
        (((unsigned long long)__float_as_uint(d2)) << 32) | (unsigned)j;
    b1 = b1 < key ? b1 : key;
  }
  const float* s2 = v2 + (size_t)b * V2N * 3;
  if (tid < V2N) {
    float d2 = sqdist_f32(cx, cy, cz, s2 + (size_t)tid * 3);
    b2 = (((unsigned long long)__float_as_uint(d2)) << 32) | (unsigned)tid;
  }
#pragma unroll
  for (int off = 32; off > 0; off >>= 1) {
    unsigned long long o1 = __shfl_down(b1, off);
    unsigned long long o2 = __shfl_down(b2, off);
    b1 = b1 < o1 ? b1 : o1;
    b2 = b2 < o2 ? b2 : o2;
  }
  if (lane == 0) { sred[wv] = b1; sred[4 + wv] = b2; }
  __syncthreads();
  if (tid == 0) {
    unsigned long long m1 = sred[0], m2 = sred[4];
#pragma unroll
    for (int r = 1; r < 4; ++r) {
      m1 = m1 < sred[r] ? m1 : sred[r];
      m2 = m2 < sred[4 + r] ? m2 : sred[4 + r];
    }
    sn12[0] = (int)(m1 & 0xffffffffu);
    sn12[1] = (int)(m2 & 0xffffffffu);
  }
  __syncthreads();
  int sn1 = sn12[0], sn2 = sn12[1];
  const float* r2 = fm2 + (size_t)bv * 96;
  const float* r5 = fm5 + ((size_t)b * V1N + sn1) * 192;
  const float* r7 = fm7 + ((size_t)b * V2N + sn2) * 256;
  const float* rg = fglob + b * 256;
  const float* roh = onehot + b * 16;
  if (tid < KP1 / 8) {
    int c = tid * 8;
    const float* src = nullptr;
    if (c < 192) {
      int cc = (c < 32) ? c : (c < 96 ? c - 32 : c - 96);
      src = r2 + cc;
    } else if (c < 672) {
      int cc = (c < 320) ? c - 192 : (c < 480 ? c - 320 : c - 480);
      src = r5 + cc;
    } else if (c < 1152) {
      int cc = (c < 896) ? c - 672 : c - 896;
      src = r7 + cc;
    } else if (c < 1408) {
      src = rg + (c - 1152);
    } else if (c < 1424) {
      src = roh + (c - 1408);
    }
    float4 lo = make_float4(0.f, 0.f, 0.f, 0.f), hi = lo;
    if (src) { lo = *(const float4*)src; hi = *(const float4*)(src + 4); }
    bf16x8 o;
    o[0] = (short)f2bf(lo.x); o[1] = (short)f2bf(lo.y);
    o[2] = (short)f2bf(lo.z); o[3] = (short)f2bf(lo.w);
    o[4] = (short)f2bf(hi.x); o[5] = (short)f2bf(hi.y);
    o[6] = (short)f2bf(hi.z); o[7] = (short)f2bf(hi.w);
    *(bf16x8*)(fuse_b + (size_t)bv * KP1 + c) = o;
  }
}

// ---------------------------------------------------------------------------
// bf16 MFMA GEMM — BK=64 + XCD swizzle + XOR-8 chunk swizzle (128² tile).
// Used for GEMM2/GEMM3.
// ---------------------------------------------------------------------------
typedef const __attribute__((address_space(1))) unsigned int gas_u32;
typedef __attribute__((address_space(3))) unsigned int las_u32;

__global__ __launch_bounds__(256) void gemm_mfma_nt(
    const ushort_t* __restrict__ A, const ushort_t* __restrict__ B,
    const float* __restrict__ bias, ushort_t* __restrict__ Cb,
    float* __restrict__ Cf, int K, int ldc, int nvalid, int mode) {
  __shared__ ushort_t As[128 * 64];
  __shared__ ushort_t Bs[128 * 64];
  int tid = threadIdx.x;
  int lane = tid & 63, w = tid >> 6;
  int wm = (w >> 1) * 64, wn = (w & 1) * 64;
  int nb = gridDim.x;
  int flat = blockIdx.x + nb * blockIdx.y;
  int xcd = flat & 7, slot = flat >> 3;
  int nidx = slot % nb;
  int mband = xcd + 8 * (slot / nb);
  int bm = mband * 128, bn = nidx * 128;
  f32x4 acc[4][4];
#pragma unroll
  for (int i = 0; i < 4; ++i)
#pragma unroll
    for (int j = 0; j < 4; ++j) acc[i][j] = (f32x4){0.f, 0.f, 0.f, 0.f};

  const ushort_t* gA[4];
  const ushort_t* gB[4];
  ushort_t* lA[4];
  ushort_t* lB[4];
  int rsub = lane >> 3;                      // row within 8-row DMA group
  int scol = ((lane & 7) ^ rsub) * 8;        // XOR-8 swizzled global chunk
#pragma unroll
  for (int g = 0; g < 4; ++g) {
    int r = w * 32 + g * 8 + rsub;
    gA[g] = A + (size_t)(bm + r) * K + scol;
    gB[g] = B + (size_t)(bn + r) * K + scol;
    lA[g] = As + (w * 32 + g * 8) * 64;
    lB[g] = Bs + (w * 32 + g * 8) * 64;
  }
  int rA = lane & 15, q = lane >> 4;
  int r7 = rA & 7;                            // row&7 for de-swizzle

  for (int k0 = 0; k0 < K; k0 += 64) {
#pragma unroll
    for (int g = 0; g < 4; ++g)
      __builtin_amdgcn_global_load_lds((gas_u32*)(gA[g] + k0), (las_u32*)lA[g],
                                       16, 0, 0);
#pragma unroll
    for (int g = 0; g < 4; ++g)
      __builtin_amdgcn_global_load_lds((gas_u32*)(gB[g] + k0), (las_u32*)lB[g],
                                       16, 0, 0);
    __syncthreads();
#pragma unroll
    for (int s = 0; s < 2; ++s) {
      int pc = ((s * 4 + q) ^ r7) * 8;        // physical chunk offset
      bf16x8 af[4], bfr[4];
#pragma unroll
      for (int i = 0; i < 4; ++i)
        af[i] = *(const bf16x8*)(As + (wm + i * 16 + rA) * 64 + pc);
#pragma unroll
      for (int j = 0; j < 4; ++j)
        bfr[j] = *(const bf16x8*)(Bs + (wn + j * 16 + rA) * 64 + pc);
#pragma unroll
      for (int i = 0; i < 4; ++i)
#pragma unroll
        for (int j = 0; j < 4; ++j)
          acc[i][j] = __builtin_amdgcn_mfma_f32_16x16x32_bf16(af[i], bfr[j],
                                                              acc[i][j], 0, 0, 0);
    }
    __syncthreads();
  }

  int rowq = (lane >> 4) * 4;
  int coll = lane & 15;
#pragma unroll
  for (int i = 0; i < 4; ++i) {
#pragma unroll
    for (int j = 0; j < 4; ++j) {
      int col = bn + wn + j * 16 + coll;
      float bi = bias[col];
#pragma unroll
      for (int r = 0; r < 4; ++r) {
        int row = bm + wm + i * 16 + rowq + r;
        float v = acc[i][j][r] + bi;
        if (mode == 0) {
          Cb[(size_t)row * ldc + col] = f2bf(fmaxf(v, 0.f));
        } else if (col < nvalid) {
          Cf[(size_t)row * ldc + col] = v;
        }
      }
    }
  }
}

// ---------------------------------------------------------------------------
// gemm256: 256×256 tile, 8 waves (2M×4N), BK=64, double-buffered LDS
// (128 KiB). R16: barrier-thinned 4-phase schedule — the 4 post-MFMA
// barriers are removed (9→5 barriers/tile). Correctness ledger: each
// wave's per-phase lgkmcnt(0) precedes its MFMA, so ALL its ds_reads of
// buf t are complete before it reaches the NEXT tile-top validity barrier;
// staging into buf t (as poff of tile t+1) is issued only after that
// barrier → no overwrite hazard. Barrier count uniform (5/tile).
// Side effect: phase q+1 reads/staging may overlap phase q MFMAs across
// waves — the R6-style overlap, now without the in-wave serialization.
// ---------------------------------------------------------------------------
__global__ __launch_bounds__(512, 2) void gemm256_mfma_nt(
    const ushort_t* __restrict__ A, const ushort_t* __restrict__ B,
    const float* __restrict__ bias, ushort_t* __restrict__ Cb,
    int K, int ldc) {
  __shared__ ushort_t As[2 * 256 * 64];   // 64 KiB
  __shared__ ushort_t Bs[2 * 256 * 64];   // 64 KiB
  int tid = threadIdx.x;
  int lane = tid & 63, w = tid >> 6;
  int wm = (w >> 2) * 128, wn = (w & 3) * 64;

  int flat = blockIdx.x;
  int xcd = flat & 7, slot = flat >> 3;
  int nidx = slot & 3, mband = xcd + 8 * (slot >> 2);
  int bm = mband * 256, bn = nidx * 256;

  f32x4 acc[8][4];
#pragma unroll
  for (int i = 0; i < 8; ++i)
#pragma unroll
    for (int j = 0; j < 4; ++j) acc[i][j] = (f32x4){0.f, 0.f, 0.f, 0.f};

  int rloc = tid >> 3, cch = tid & 7;
  int gc = (cch ^ (rloc & 7)) * 8;
  const ushort_t* gA[4];
  const ushort_t* gB[4];
#pragma unroll
  for (int i = 0; i < 4; ++i) {
    gA[i] = A + (size_t)(bm + i * 64 + rloc) * K + gc;
    gB[i] = B + (size_t)(bn + i * 64 + rloc) * K + gc;
  }
  int lofs = tid * 8;

  int rA = lane & 15, r7 = lane & 7;
  int qlane = lane >> 4;
  int pc0 = (qlane ^ r7) * 8;         // physical chunk col, k-half 0
  int pc1 = ((4 + qlane) ^ r7) * 8;   // physical chunk col, k-half 1

  int NT = K >> 6;

  // prologue: stage tile 0 into buffer 0
#pragma unroll
  for (int i = 0; i < 4; ++i) {
    __builtin_amdgcn_global_load_lds((gas_u32*)gA[i],
                                     (las_u32*)(As + i * 4096 + lofs), 16, 0, 0);
    gA[i] += 64;
  }
#pragma unroll
  for (int i = 0; i < 4; ++i) {
    __builtin_amdgcn_global_load_lds((gas_u32*)gB[i],
                                     (las_u32*)(Bs + i * 4096 + lofs), 16, 0, 0);
    gB[i] += 64;
  }

  for (int t = 0; t < NT; ++t) {
    int doff = (t & 1) * 16384;
    int poff = doff ^ 16384;
    const ushort_t* Ab = As + doff;
    const ushort_t* Bb = Bs + doff;
    bool pf = (t + 1 < NT);

    // tile-validity: own loads landed, then barrier so ALL waves' staged
    // chunks of tile t are visible before any ds_read of it. Also proves
    // all waves drained their buf t-1 reads (per-phase lgkmcnt(0) below).
    asm volatile("s_waitcnt vmcnt(0)" ::: "memory");
    __builtin_amdgcn_sched_barrier(0);
    __builtin_amdgcn_s_barrier();
    __builtin_amdgcn_sched_barrier(0);

#pragma unroll
    for (int q = 0; q < 4; ++q) {
      int band = q >> 1, kh = q & 1;
      int pck = kh ? pc1 : pc0;

      // phase reads issued first: 4 A-band frags + 4 B frags (8 × b128)
      bf16x8 af[4], bfq[4];
#pragma unroll
      for (int fi = 0; fi < 4; ++fi)
        af[fi] = *(const bf16x8*)(Ab + (wm + band * 64 + fi * 16 + rA) * 64 + pck);
#pragma unroll
      for (int fj = 0; fj < 4; ++fj)
        bfq[fj] = *(const bf16x8*)(Bb + (wn + fj * 16 + rA) * 64 + pck);

      // stage 2 chunks of tile t+1 (phases 0,1 -> A halves; 2,3 -> B halves)
      if (pf) {
        if (q < 2) {
          __builtin_amdgcn_global_load_lds(
              (gas_u32*)gA[2 * q],
              (las_u32*)(As + poff + (2 * q) * 4096 + lofs), 16, 0, 0);
          __builtin_amdgcn_global_load_lds(
              (gas_u32*)gA[2 * q + 1],
              (las_u32*)(As + poff + (2 * q + 1) * 4096 + lofs), 16, 0, 0);
          gA[2 * q] += 64;
          gA[2 * q + 1] += 64;
        } else {
          int i = 2 * (q - 2);
          __builtin_amdgcn_global_load_lds(
              (gas_u32*)gB[i],
              (las_u32*)(Bs + poff + i * 4096 + lofs), 16, 0, 0);
          __builtin_amdgcn_global_load_lds(
              (gas_u32*)gB[i + 1],
              (las_u32*)(Bs + poff + (i + 1) * 4096 + lofs), 16, 0, 0);
          gB[i] += 64;
          gB[i + 1] += 64;
        }
      }

      __builtin_amdgcn_sched_barrier(0);
      __builtin_amdgcn_s_barrier();
      asm volatile("s_waitcnt lgkmcnt(0)" ::: "memory");
      __builtin_amdgcn_sched_barrier(0);

      __builtin_amdgcn_s_setprio(1);
#pragma unroll
      for (int fi = 0; fi < 4; ++fi)
#pragma unroll
        for (int fj = 0; fj < 4; ++fj)
          acc[band * 4 + fi][fj] = __builtin_amdgcn_mfma_f32_16x16x32_bf16(
              af[fi], bfq[fj], acc[band * 4 + fi][fj], 0, 0, 0);
      __builtin_amdgcn_s_setprio(0);
      __builtin_amdgcn_sched_barrier(0);
      // R16: post-MFMA barrier removed (see ledger in header comment)
    }
  }

  int rowq = (lane >> 4) * 4;
  int coll = lane & 15;
  float bi[4];
#pragma unroll
  for (int j = 0; j < 4; ++j) bi[j] = bias[bn + wn + j * 16 + coll];
#pragma unroll
  for (int i = 0; i < 8; ++i) {
#pragma unroll
    for (int j = 0; j < 4; ++j) {
      int col = bn + wn + j * 16 + coll;
#pragma unroll
      for (int r = 0; r < 4; ++r) {
        int row = bm + wm + i * 16 + rowq + r;
        float v = acc[i][j][r] + bi[j];
        Cb[(size_t)row * ldc + col] = f2bf(fmaxf(v, 0.f));
      }
    }
  }
}

// ---------------------------------------------------------------------------
extern "C" void kernel_launch(void* const* d_in, const int* in_sizes, int n_in,
                              void* d_out, int out_size, void* d_ws,
                              size_t ws_size, hipStream_t stream) {
  const float* vertices = (const float*)d_in[0];
  const float* onehot = (const float*)d_in[1];
  const float* d0 = (const float*)d_in[2];
  const float *w[8], *bb[8], *dd[8];
  for (int i = 1; i <= 7; ++i) {
    w[i] = (const float*)d_in[3 * i];
    bb[i] = (const float*)d_in[3 * i + 1];
    dd[i] = (const float*)d_in[3 * i + 2];
  }
  const float* cw1 = (const float*)d_in[24];
  const float* cb1 = (const float*)d_in[25];
  const float* cw2 = (const float*)d_in[26];
  const float* cb2 = (const float*)d_in[27];
  const float* cw3 = (const float*)d_in[28];
  const float* cb3 = (const float*)d_in[29];
  float* out = (float*)d_out;

  char* wsp = (char*)d_ws;
  size_t off = 0;
  auto alloc = [&](size_t bytes) -> void* {
    void* p = wsp + off;
    off += (bytes + 255) & ~(size_t)255;
    return p;
  };
  const int M = BS * V0;  // 16384
  int* rank = (int*)alloc(4608 * 4);
  int* perm1 = (int*)alloc(512 * 4);
  int* perm2 = (int*)alloc(128 * 4);
  int* ni1 = (int*)alloc((size_t)BS * V0 * 32 * 4);
  int* ni2 = (int*)alloc((size_t)BS * V1N * 32 * 4);
  int* ni3 = (int*)alloc((size_t)BS * V2N * 32 * 4);
  float* fm2buf = (float*)alloc((size_t)BS * V0 * 96 * 4);
  float* fm5buf = (float*)alloc((size_t)BS * V1N * 192 * 4);
  float* fm7buf = (float*)alloc((size_t)BS * V2N * 256 * 4);
  float* fbuf = (float*)alloc((size_t)BS * V0 * 64 * 4);
  float* v1 = (float*)alloc((size_t)BS * V1N * 3 * 4);
  float* v2 = (float*)alloc((size_t)BS * V2N * 3 * 4);
  float* fglob = (float*)alloc((size_t)BS * 256 * 4);
  ushort_t* fuse_b = (ushort_t*)alloc((size_t)M * KP1 * 2);
  ushort_t* h1b = (ushort_t*)alloc((size_t)M * 1024 * 2);
  ushort_t* h2b = (ushort_t*)alloc((size_t)M * 512 * 2);
  ushort_t* cw1b = (ushort_t*)alloc((size_t)1024 * KP1 * 2);
  ushort_t* cw2b = (ushort_t*)alloc((size_t)512 * 1024 * 2);
  ushort_t* cw3b = (ushort_t*)alloc((size_t)128 * 512 * 2);
  float* cb3p = (float*)alloc(128 * 4);

  float rr1 = 0.0625f;
  float rr2 = (float)(0.39 * 0.39);
  float rr3 = (float)(0.63 * 0.63);

  // 0: zero rank accumulators (async, stream-ordered; graph-capture-safe)
  hipMemsetAsync(rank, 0, 4608 * 4, stream);
  // 1: weight-prep + qbp1
  misc1_kernel<<<PREP_BLKS + QBP1_BLKS, 256, 0, stream>>>(
      cw1, cw2, cw3, cb3, cw1b, cw2b, cw3b, cb3p, vertices, ni1);
  // 2: scan-split rank (288 partial blocks, hidden) + conv_surface(+linear1)
  misc2_kernel<<<RANK_BLKS + BS * V0 / 8, 256, 0, stream>>>(
      rank, vertices, ni1, d0, w[1], bb[1], fm2buf, fbuf);
  // 2b: perm compose (needs rank; before pool1)
  perm_kernel<<<1, 256, 0, stream>>>(rank, perm1, perm2);
  // 3-4: level-1 convs
  conv_act_kernel<<<BS * V0 / 8, 256, 0, stream>>>(
      vertices, dd[1], ni1, fbuf, fm2buf, V0, 96, 32, w[2], bb[2], fbuf);
  conv_act_kernel<<<BS * V0 / 8, 256, 0, stream>>>(
      vertices, dd[2], ni1, fbuf, fm2buf, V0, 96, 64, nullptr, nullptr, nullptr);
  // 5: pool1 (+linear3)
  pool_kernel<<<BS * V1N / 4, 256, 0, stream>>>(
      vertices, fm2buf, 96, 96, V0, perm1, V1N, rr1, v1, fm5buf, 192,
      w[3], bb[3], fbuf);
  // 6-8: level-2 convs (first fuses qbp2 + linear4)
  conv_act_qbp_kernel<<<BS * V1N / 8, 256, 0, stream>>>(
      v1, V1N, rr2, dd[3], ni2, fbuf, fm5buf, 192, 96, w[4], bb[4], fbuf);
  conv_act_kernel<<<BS * V1N / 8, 256, 0, stream>>>(
      v1, dd[4], ni2, fbuf, fm5buf, V1N, 192, 128, w[5], bb[5], fbuf);
  conv_act_kernel<<<BS * V1N / 8, 256, 0, stream>>>(
      v1, dd[5], ni2, fbuf, fm5buf, V1N, 192, 160, nullptr, nullptr, nullptr);
  // 9: pool2 (+linear6)
  pool_kernel<<<BS * V2N / 4, 256, 0, stream>>>(
      v1, fm5buf, 192, 192, V1N, perm2, V2N, rr2, v2, fm7buf, 256,
      w[6], bb[6], fbuf);
  // 10-11: level-3 convs (first fuses qbp3 + linear7)
  conv_act_qbp_kernel<<<BS * V2N / 8, 256, 0, stream>>>(
      v2, V2N, rr3, dd[6], ni3, fbuf, fm7buf, 256, 192, w[7], bb[7], fbuf);
  conv_act_kernel<<<BS * V2N / 8, 256, 0, stream>>>(
      v2, dd[7], ni3, fbuf, fm7buf, V2N, 256, 224, nullptr, nullptr, nullptr);
  // 12: global max (64 blocks, coalesced)
  gmax_kernel<<<64, 256, 0, stream>>>(fm7buf, fglob);
  // 13: fused nearest + gather + bf16 cast (wave-shuffle argmin)
  fuse_row_kernel<<<M, 256, 0, stream>>>(fm2buf, fm5buf, fm7buf, fglob, onehot,
                                         vertices, v1, v2, fuse_b);
  // 14: MLP layer 1 — 256² barrier-thinned 4-phase schedule
  gemm256_mfma_nt<<<(M / 256) * (1024 / 256), 512, 0, stream>>>(
      fuse_b, cw1b, cb1, h1b, KP1, 1024);
  // 15-16: MLP layers 2-3 (128² kernel)
  gemm_mfma_nt<<<dim3(512 / 128, M / 128), 256, 0, stream>>>(
      h1b, cw2b, cb2, h2b, nullptr, 1024, 512, 512, 0);
  gemm_mfma_nt<<<dim3(1, M / 128), 256, 0, stream>>>(
      h2b, cw3b, cb3p, nullptr, out, 512, 50, 50, 1);
}

// Round 17
// 368.535 us; speedup vs baseline: 1.0096x; 1.0096x over previous
//
#include <hip/hip_runtime.h>
#include <hip/hip_bf16.h>

#define BS 8
#define V0 2048
#define V1N 512
#define V2N 128

typedef unsigned short ushort_t;
typedef __attribute__((ext_vector_type(8))) short bf16x8;
typedef __attribute__((ext_vector_type(4))) float f32x4;

// ---------------------------------------------------------------------------
// Threefry2x32 cipher (JAX partitionable mode — verified R4)
// ---------------------------------------------------------------------------
__device__ __forceinline__ void tf2x32(unsigned k0, unsigned k1,
                                       unsigned x0, unsigned x1,
                                       unsigned &o0, unsigned &o1) {
  unsigned ks2 = k0 ^ k1 ^ 0x1BD11BDAu;
  x0 += k0; x1 += k1;
#define RR(r) { x0 += x1; x1 = (x1 << (r)) | (x1 >> (32 - (r))); x1 ^= x0; }
  RR(13) RR(15) RR(26) RR(6)   x0 += k1;  x1 += ks2 + 1u;
  RR(17) RR(29) RR(16) RR(24)  x0 += ks2; x1 += k0 + 2u;
  RR(13) RR(15) RR(26) RR(6)   x0 += k0;  x1 += k1 + 3u;
  RR(17) RR(29) RR(16) RR(24)  x0 += k1;  x1 += ks2 + 4u;
  RR(13) RR(15) RR(26) RR(6)   x0 += ks2; x1 += k0 + 5u;
#undef RR
  o0 = x0; o1 = x1;
}

__device__ __forceinline__ ushort_t f2bf(float f) {
  unsigned u = __float_as_uint(f);
  u += 0x7FFFu + ((u >> 16) & 1u);
  return (ushort_t)(u >> 16);
}

__device__ __forceinline__ float sqdist_f32(float cx, float cy, float cz,
                                            const float* p) {
  float dx = __fsub_rn(cx, p[0]);
  float dy = __fsub_rn(cy, p[1]);
  float dz = __fsub_rn(cz, p[2]);
  return __fadd_rn(__fadd_rn(__fmul_rn(dx, dx), __fmul_rn(dy, dy)),
                   __fmul_rn(dz, dz));
}

#define KP1 1472   // 1424 real + zero pad to 64-multiple (BK=64)

// ---------------------------------------------------------------------------
// misc1: [0,PREP_BLKS) vectorized weight prep · then qbp lvl-1 (LDS-staged).
// ---------------------------------------------------------------------------
#define PREP_BLKS 1025   // 262,160 8-elem chunks / 256
#define QBP1_BLKS 512    // 16384 queries / 32
__global__ __launch_bounds__(256) void misc1_kernel(
    const float* __restrict__ cw1, const float* __restrict__ cw2,
    const float* __restrict__ cw3, const float* __restrict__ cb3,
    ushort_t* __restrict__ cw1b, ushort_t* __restrict__ cw2b,
    ushort_t* __restrict__ cw3b, float* __restrict__ cb3p,
    const float* __restrict__ pts, int* __restrict__ ni1) {
  int bid = blockIdx.x, tid = threadIdx.x;
  if (bid < PREP_BLKS) {
    int c = bid * 256 + tid;
    const int C1 = 1024 * (KP1 / 8);          // 188416
    const int C2 = (512 * 1024) / 8;          // 65536
    const int C3 = (128 * 512) / 8;           // 8192
    if (c < C1) {
      int n = c / (KP1 / 8);
      int cc = c - n * (KP1 / 8);
      int k = cc * 8;
      bf16x8 o = (bf16x8){0, 0, 0, 0, 0, 0, 0, 0};
      if (k < 1424) {                        // 1424 % 8 == 0: fully real
        const float* src = cw1 + (size_t)n * 1424 + k;
        float4 lo = *(const float4*)src;
        float4 hi = *(const float4*)(src + 4);
        o[0] = (short)f2bf(lo.x); o[1] = (short)f2bf(lo.y);
        o[2] = (short)f2bf(lo.z); o[3] = (short)f2bf(lo.w);
        o[4] = (short)f2bf(hi.x); o[5] = (short)f2bf(hi.y);
        o[6] = (short)f2bf(hi.z); o[7] = (short)f2bf(hi.w);
      }
      *(bf16x8*)(cw1b + (size_t)c * 8) = o;
    } else if (c < C1 + C2) {
      int u = (c - C1) * 8;
      const float* src = cw2 + u;
      float4 lo = *(const float4*)src;
      float4 hi = *(const float4*)(src + 4);
      bf16x8 o;
      o[0] = (short)f2bf(lo.x); o[1] = (short)f2bf(lo.y);
      o[2] = (short)f2bf(lo.z); o[3] = (short)f2bf(lo.w);
      o[4] = (short)f2bf(hi.x); o[5] = (short)f2bf(hi.y);
      o[6] = (short)f2bf(hi.z); o[7] = (short)f2bf(hi.w);
      *(bf16x8*)(cw2b + u) = o;
    } else if (c < C1 + C2 + C3) {
      int u = (c - C1 - C2) * 8;
      int n = u >> 9, k = u & 511;
      bf16x8 o = (bf16x8){0, 0, 0, 0, 0, 0, 0, 0};
      if (n < 50) {
        const float* src = cw3 + (size_t)n * 512 + k;
        float4 lo = *(const float4*)src;
        float4 hi = *(const float4*)(src + 4);
        o[0] = (short)f2bf(lo.x); o[1] = (short)f2bf(lo.y);
        o[2] = (short)f2bf(lo.z); o[3] = (short)f2bf(lo.w);
        o[4] = (short)f2bf(hi.x); o[5] = (short)f2bf(hi.y);
        o[6] = (short)f2bf(hi.z); o[7] = (short)f2bf(hi.w);
      }
      *(bf16x8*)(cw3b + u) = o;
    } else if (c < C1 + C2 + C3 + 16) {
      int u = (c - C1 - C2 - C3) * 8;
#pragma unroll
      for (int e = 0; e < 8; ++e)
        cb3p[u + e] = (u + e) < 50 ? cb3[u + e] : 0.f;
    }
  } else {
    // qbp level-1: stage batch's 2048 pts into LDS once, serve 32 queries.
    __shared__ float spts[V0 * 3];   // 24 KiB
    int bq = bid - PREP_BLKS;        // 0..511
    int qbase = bq * 32;             // 64 blocks per batch (2048 % 32 == 0)
    int b = qbase >> 11;
    const float* base = pts + (size_t)b * V0 * 3;
    for (int i = tid; i < V0 * 3 / 4; i += 256)
      ((float4*)spts)[i] = ((const float4*)base)[i];
    __syncthreads();
    int lane = tid & 63, wv = tid >> 6;
    for (int rep = 0; rep < 8; ++rep) {
      int qoff = wv * 8 + rep;
      int qi = (qbase & 2047) + qoff;
      int wid = qbase + qoff;
      float cx = spts[qi * 3], cy = spts[qi * 3 + 1], cz = spts[qi * 3 + 2];
      int cnt = 0, idx0 = 0;
      for (int j0 = 0; j0 < V0; j0 += 64) {
        int j = j0 + lane;
        float d2 = sqdist_f32(cx, cy, cz, spts + (size_t)j * 3);
        bool in = (d2 <= 0.0625f);
        unsigned long long mask = __ballot(in);
        if (cnt == 0 && mask) idx0 = j0 + __builtin_ctzll(mask);
        if (in) {
          int rk = cnt + __popcll(mask & ((1ull << lane) - 1ull));
          if (rk < 32) ni1[(size_t)wid * 32 + rk] = j;
        }
        cnt += __popcll(mask);
        if (cnt >= 32) break;
      }
      for (int s = cnt + lane; s < 32; s += 64) ni1[(size_t)wid * 32 + s] = idx0;
    }
  }
}

// ---------------------------------------------------------------------------
__device__ __forceinline__ void dirn(const float* base, int v, int nb,
                                     float& ox, float& oy, float& oz) {
  float dx = __fsub_rn(base[nb * 3 + 0], base[v * 3 + 0]);
  float dy = __fsub_rn(base[nb * 3 + 1], base[v * 3 + 1]);
  float dz = __fsub_rn(base[nb * 3 + 2], base[v * 3 + 2]);
  float s2 = __fadd_rn(__fadd_rn(__fmul_rn(dx, dx), __fmul_rn(dy, dy)),
                       __fmul_rn(dz, dz));
  float nrm = fmaxf(__fsqrt_rn(s2), 1e-12f);
  ox = __fdiv_rn(dx, nrm); oy = __fdiv_rn(dy, nrm); oz = __fdiv_rn(dz, nrm);
}

__device__ __forceinline__ void norm_col(const float* d, int k,
                                         float& ox, float& oy, float& oz) {
  float x = d[k], y = d[32 + k], z = d[64 + k];
  float s2 = __fadd_rn(__fadd_rn(__fmul_rn(x, x), __fmul_rn(y, y)),
                       __fmul_rn(z, z));
  float nrm = fmaxf(__fsqrt_rn(s2), 1e-12f);
  ox = __fdiv_rn(x, nrm); oy = __fdiv_rn(y, nrm); oz = __fdiv_rn(z, nrm);
}

// ---------------------------------------------------------------------------
// misc2: blocks [0,RANK_BLKS) = scan-split threefry rank (R15-verified:
// partial counts atomicAdd'd, hidden under conv_surface);
// blocks [RANK_BLKS, +2048) = conv_surface (+linear1).
// ---------------------------------------------------------------------------
#define RANK_PARTS 16
#define RANK_BLKS (18 * RANK_PARTS)
__global__ __launch_bounds__(256) void misc2_kernel(
    int* __restrict__ rank, const float* __restrict__ pts,
    const int* __restrict__ ni, const float* __restrict__ d0,
    const float* __restrict__ w1, const float* __restrict__ b1,
    float* __restrict__ out, float* __restrict__ fn) {
  int bid = blockIdx.x, tid = threadIdx.x;
  if (bid < RANK_BLKS) {
    __shared__ unsigned sb[128];
    int rid = bid >> 4, part = bid & (RANK_PARTS - 1);
    int seg, segfirst, n, base;
    if (rid < 8)       { seg = 0; segfirst = 0;  n = 2048; base = 0; }
    else if (rid < 16) { seg = 1; segfirst = 8;  n = 2048; base = 2048; }
    else               { seg = 2; segfirst = 16; n = 512;  base = 4096; }
    unsigned k0, k1, nk0, nk1, sk0, sk1;
    if (seg == 0) {
      tf2x32(0u, 42u, 0u, 1u, k0, k1);
      tf2x32(k0, k1, 0u, 1u, sk0, sk1);
    } else if (seg == 1) {
      tf2x32(0u, 42u, 0u, 1u, k0, k1);
      tf2x32(k0, k1, 0u, 0u, nk0, nk1);
      tf2x32(nk0, nk1, 0u, 1u, sk0, sk1);
    } else {
      tf2x32(0u, 42u, 0u, 2u, k0, k1);
      tf2x32(k0, k1, 0u, 1u, sk0, sk1);
    }
    int chunk = n / RANK_PARTS;        // 128 (n=2048) or 32 (n=512)
    int s0 = part * chunk;
    for (int i = tid; i < chunk; i += 256) {
      unsigned o0, o1;
      tf2x32(sk0, sk1, 0u, (unsigned)(s0 + i), o0, o1);
      sb[i] = o0 ^ o1;
    }
    __syncthreads();
    int tt = (rid - segfirst) * 256 + tid;
    unsigned o0, o1;
    tf2x32(sk0, sk1, 0u, (unsigned)tt, o0, o1);
    unsigned bt = o0 ^ o1;
    int cnt = 0;
#pragma unroll 8
    for (int j = 0; j < chunk; ++j) {
      unsigned bs = sb[j];
      cnt += (bs < bt) || (bs == bt && (s0 + j) < tt);
    }
    atomicAdd(&rank[base + tt], cnt);
    return;
  }
  __shared__ float sdir[3][32];
  __shared__ float sdn[8][32][3];
  __shared__ float sfm[8][32];
  if (tid < 32) {
    float x, y, z; norm_col(d0, tid, x, y, z);
    sdir[0][tid] = x; sdir[1][tid] = y; sdir[2][tid] = z;
  }
  int vloc = tid >> 5, k = tid & 31;
  size_t bvg = (size_t)(bid - RANK_BLKS) * 8 + vloc;
  int b = (int)(bvg >> 11), v = (int)(bvg & 2047);
  const float* base = pts + (size_t)b * V0 * 3;
  int nb = ni[bvg * 32 + k];
  float x, y, z; dirn(base, v, nb, x, y, z);
  sdn[vloc][k][0] = x; sdn[vloc][k][1] = y; sdn[vloc][k][2] = z;
  __syncthreads();
  float m = 0.f;
  for (int n = 0; n < 32; ++n) {
    float d = sdn[vloc][n][0] * sdir[0][k] + sdn[vloc][n][1] * sdir[1][k] +
              sdn[vloc][n][2] * sdir[2][k];
    m = fmaxf(m, fmaxf(d, 0.f));
  }
  out[bvg * 96 + k] = m;
  sfm[vloc][k] = m;
  __syncthreads();
  float a1v = b1[k], a2v = b1[k + 32];
  for (int c = 0; c < 32; ++c) {
    float vv = sfm[vloc][c];
    a1v += vv * w1[c * 64 + k];
    a2v += vv * w1[c * 64 + k + 32];
  }
  fn[bvg * 64 + k] = a1v;
  fn[bvg * 64 + k + 32] = a2v;
}

// ---------------------------------------------------------------------------
// perm_kernel: compose permutations from rank.
// ---------------------------------------------------------------------------
__global__ __launch_bounds__(256) void perm_kernel(
    const int* __restrict__ rank, int* __restrict__ perm1,
    int* __restrict__ perm2) {
  int tid = threadIdx.x;
  __shared__ int a1[2048];
  __shared__ int a2[2048];
  for (int i = tid; i < 2048; i += 256) a1[rank[i]] = i;
  __syncthreads();
  for (int i = tid; i < 2048; i += 256) a2[rank[2048 + i]] = a1[i];
  __syncthreads();
  for (int i = tid; i < 512; i += 256) perm1[i] = a2[i];
  for (int i = tid; i < 512; i += 256) a1[rank[4096 + i]] = i;
  __syncthreads();
  for (int i = tid; i < 128; i += 256) perm2[i] = a1[i];
}

// ---------------------------------------------------------------------------
// conv_act (+ optional fused next-linear)
// ---------------------------------------------------------------------------
__global__ __launch_bounds__(256) void conv_act_kernel(
    const float* __restrict__ pts, const float* __restrict__ dd,
    const int* __restrict__ ni, const float* __restrict__ f,
    float* __restrict__ out, int Nv, int ldout, int colofs,
    const float* __restrict__ wn, const float* __restrict__ bn,
    float* __restrict__ fn) {
  __shared__ float sdir[3][32];
  __shared__ float sdn[8][32][3];
  __shared__ int sidx[8][32];
  __shared__ float sfm[8][256];
  int tid = threadIdx.x;
  if (tid < 32) {
    float x, y, z; norm_col(dd, tid, x, y, z);
    sdir[0][tid] = x; sdir[1][tid] = y; sdir[2][tid] = z;
  }
  int vloc = tid >> 5, k = tid & 31;
  size_t bvg = (size_t)blockIdx.x * 8 + vloc;
  int b = (int)(bvg / Nv), v = (int)(bvg % Nv);
  const float* base = pts + (size_t)b * Nv * 3;
  int nb = ni[bvg * 32 + k];
  float x, y, z; dirn(base, v, nb, x, y, z);
  sdn[vloc][k][0] = x; sdn[vloc][k][1] = y; sdn[vloc][k][2] = z;
  sidx[vloc][k] = nb;
  __syncthreads();
  float m = -INFINITY;
  size_t fb = (size_t)b * Nv * 64;
  for (int n = 0; n < 32; ++n) {
    float th = fmaxf(sdn[vloc][n][0] * sdir[0][k] + sdn[vloc][n][1] * sdir[1][k] +
                     sdn[vloc][n][2] * sdir[2][k], 0.f);
    float sup = f[fb + (size_t)sidx[vloc][n] * 64 + 32 + k];
    m = fmaxf(m, th * sup);
  }
  float center = f[bvg * 64 + k];
  float res = fmaxf(center + m, 0.f);
  out[bvg * ldout + colofs + k] = res;
  if (wn) {
    size_t rowbase = (size_t)blockIdx.x * 8;
#pragma unroll 1
    for (int r = 0; r < 8; ++r)
      if (tid < colofs) sfm[r][tid] = out[(rowbase + r) * ldout + tid];
    sfm[vloc][colofs + k] = res;
    __syncthreads();
    int cin = colofs + 32;
    float a1v = bn[k], a2v = bn[k + 32];
    for (int c = 0; c < cin; ++c) {
      float vv = sfm[vloc][c];
      a1v += vv * wn[c * 64 + k];
      a2v += vv * wn[c * 64 + k + 32];
    }
    fn[bvg * 64 + k] = a1v;
    fn[bvg * 64 + k + 32] = a2v;
  }
}

// ---------------------------------------------------------------------------
// conv_act_qbp: qbp fused in front of conv_act (+fused linear)
// ---------------------------------------------------------------------------
__global__ __launch_bounds__(256) void conv_act_qbp_kernel(
    const float* __restrict__ pts, int Nv, float rrq,
    const float* __restrict__ dd, int* __restrict__ ni_out,
    const float* __restrict__ f, float* __restrict__ out, int ldout,
    int colofs, const float* __restrict__ wn, const float* __restrict__ bn,
    float* __restrict__ fn) {
  __shared__ float spts[512 * 3];
  __shared__ float sdir[3][32];
  __shared__ float sdn[8][32][3];
  __shared__ int sni[8][32];
  __shared__ float sfm[8][256];
  int tid = threadIdx.x;
  int b = (blockIdx.x * 8) / Nv;
  int vbase = (blockIdx.x * 8) % Nv;
  const float* gp = pts + (size_t)b * Nv * 3;
  for (int i = tid; i < Nv * 3; i += 256) spts[i] = gp[i];
  if (tid < 32) {
    float x, y, z; norm_col(dd, tid, x, y, z);
    sdir[0][tid] = x; sdir[1][tid] = y; sdir[2][tid] = z;
  }
  __syncthreads();
  int lane = tid & 63, wv = tid >> 6;
  for (int rep = 0; rep < 2; ++rep) {
    int vl = wv * 2 + rep;
    int v = vbase + vl;
    float cx = spts[v * 3], cy = spts[v * 3 + 1], cz = spts[v * 3 + 2];
    int cnt = 0, idx0 = 0;
    for (int j0 = 0; j0 < Nv; j0 += 64) {
      int j = j0 + lane;
      float d2 = sqdist_f32(cx, cy, cz, spts + (size_t)j * 3);
      bool in = (d2 <= rrq);
      unsigned long long mask = __ballot(in);
      if (cnt == 0 && mask) idx0 = j0 + __builtin_ctzll(mask);
      if (in) {
        int rk = cnt + __popcll(mask & ((1ull << lane) - 1ull));
        if (rk < 32) sni[vl][rk] = j;
      }
      cnt += __popcll(mask);
      if (cnt >= 32) break;
    }
    for (int s = cnt + lane; s < 32; s += 64) sni[vl][s] = idx0;
  }
  __syncthreads();
  ni_out[(size_t)(blockIdx.x * 8) * 32 + tid] = sni[tid >> 5][tid & 31];
  int vloc = tid >> 5, k = tid & 31;
  size_t bvg = (size_t)blockIdx.x * 8 + vloc;
  int v = vbase + vloc;
  int nb = sni[vloc][k];
  float x, y, z; dirn(spts, v, nb, x, y, z);
  sdn[vloc][k][0] = x; sdn[vloc][k][1] = y; sdn[vloc][k][2] = z;
  __syncthreads();
  float m = -INFINITY;
  size_t fb = (size_t)b * Nv * 64;
  for (int n = 0; n < 32; ++n) {
    float th = fmaxf(sdn[vloc][n][0] * sdir[0][k] + sdn[vloc][n][1] * sdir[1][k] +
                     sdn[vloc][n][2] * sdir[2][k], 0.f);
    float sup = f[fb + (size_t)sni[vloc][n] * 64 + 32 + k];
    m = fmaxf(m, th * sup);
  }
  float center = f[bvg * 64 + k];
  float res = fmaxf(center + m, 0.f);
  out[bvg * ldout + colofs + k] = res;
  size_t rowbase = (size_t)blockIdx.x * 8;
#pragma unroll 1
  for (int r = 0; r < 8; ++r)
    if (tid < colofs) sfm[r][tid] = out[(rowbase + r) * ldout + tid];
  sfm[vloc][colofs + k] = res;
  __syncthreads();
  int cin = colofs + 32;
  float a1v = bn[k], a2v = bn[k + 32];
  for (int c = 0; c < cin; ++c) {
    float vv = sfm[vloc][c];
    a1v += vv * wn[c * 64 + k];
    a2v += vv * wn[c * 64 + k + 32];
  }
  fn[bvg * 64 + k] = a1v;
  fn[bvg * 64 + k + 32] = a2v;
}

// ---------------------------------------------------------------------------
// pool (+ fused next-linear)
// ---------------------------------------------------------------------------
__global__ __launch_bounds__(256) void pool_kernel(
    const float* __restrict__ pts_in, const float* __restrict__ fm_in,
    int ld_in, int C, int Nv_in, const int* __restrict__ perm, int Nv_out,
    float rr, float* __restrict__ pts_out, float* __restrict__ fm_out,
    int ld_out, const float* __restrict__ wn, const float* __restrict__ bn,
    float* __restrict__ fn) {
  __shared__ float spf[4][192];
  int wv = threadIdx.x >> 6;
  int lane = threadIdx.x & 63;
  int wid = blockIdx.x * 4 + wv;
  int b = wid / Nv_out, pp = wid - b * Nv_out;
  int v = perm[pp];
  const float* base = pts_in + (size_t)b * Nv_in * 3;
  float cx = base[v * 3], cy = base[v * 3 + 1], cz = base[v * 3 + 2];
  int nb[4]; int cnt = 0;
  for (int j0 = 0; j0 < Nv_in && cnt < 4; j0 += 64) {
    int j = j0 + lane;
    float d2 = sqdist_f32(cx, cy, cz, base + (size_t)j * 3);
    unsigned long long mask = __ballot(d2 <= rr);
    while (mask && cnt < 4) {
      int bp = __builtin_ctzll(mask);
      mask &= mask - 1;
      nb[cnt++] = j0 + bp;
    }
  }
  for (int q = cnt; q < 4; ++q) nb[q] = nb[0];
  if (lane < 3) pts_out[(size_t)wid * 3 + lane] = base[v * 3 + lane];
  size_t inrow = (size_t)b * Nv_in;
  size_t outrow = (size_t)wid * ld_out;
  for (int c = lane; c < C; c += 64) {
    float m = fm_in[(inrow + nb[0]) * ld_in + c];
    m = fmaxf(m, fm_in[(inrow + nb[1]) * ld_in + c]);
    m = fmaxf(m, fm_in[(inrow + nb[2]) * ld_in + c]);
    m = fmaxf(m, fm_in[(inrow + nb[3]) * ld_in + c]);
    fm_out[outrow + c] = m;
    spf[wv][c] = m;
  }
  __syncthreads();
  int o = threadIdx.x & 63, w_ = threadIdx.x >> 6;
  int wid0 = blockIdx.x * 4 + w_;
  float a = bn[o];
  for (int c = 0; c < C; ++c) a += spf[w_][c] * wn[c * 64 + o];
  fn[(size_t)wid0 * 64 + o] = a;
}

// ---------------------------------------------------------------------------
// gmax: grid 64 = 8 batches × 8 col-groups; 256 thr = 8 v-sub × 32 cols.
// ---------------------------------------------------------------------------
__global__ __launch_bounds__(256) void gmax_kernel(
    const float* __restrict__ fm, float* __restrict__ out) {
  __shared__ float red[8][32];
  int b = blockIdx.x >> 3, cg = blockIdx.x & 7;
  int vsub = threadIdx.x >> 5, cl = threadIdx.x & 31;
  int c = cg * 32 + cl;
  float m = -INFINITY;
  for (int v = vsub; v < V2N; v += 8)
    m = fmaxf(m, fm[((size_t)b * V2N + v) * 256 + c]);
  red[vsub][cl] = m;
  __syncthreads();
  if (vsub == 0) {
#pragma unroll
    for (int r = 1; r < 8; ++r) m = fmaxf(m, red[r][cl]);
    out[b * 256 + c] = m;
  }
}

// ---------------------------------------------------------------------------
// fuse_row: wave-level shuffle argmin + gather (R7/R8 verified)
// ---------------------------------------------------------------------------
__global__ __launch_bounds__(256) void fuse_row_kernel(
    const float* __restrict__ fm2, const float* __restrict__ fm5,
    const float* __restrict__ fm7, const float* __restrict__ fglob,
    const float* __restrict__ onehot, const float* __restrict__ verts,
    const float* __restrict__ v1, const float* __restrict__ v2,
    ushort_t* __restrict__ fuse_b) {
  __shared__ unsigned long long sred[8];   // [0..3]=v1 per-wave, [4..7]=v2
  __shared__ int sn12[2];
  int bv = blockIdx.x;
  int b = bv >> 11;
  int tid = threadIdx.x;
  int lane = tid & 63, wv = tid >> 6;
  float cx = verts[(size_t)bv * 3 + 0];
  float cy = verts[(size_t)bv * 3 + 1];
  float cz = verts[(size_t)bv * 3 + 2];
  unsigned long long b1 = ~0ull, b2 = ~0ull;
  const float* s1 = v1 + (size_t)b * V1N * 3;
  for (int j = tid; j < V1N; j += 256) {
    float d2 = sqdist_f32(cx, cy, cz, s1 + (size_t)j * 3);
    unsigned long long key =
        (((unsigned long long)__float_as_uint(d2)) << 32) | (unsigned)j;
    b1 = b1 < key ? b1 : key;
  }
  const float* s2 = v2 + (size_t)b * V2N * 3;
  if (tid < V2N) {
    float d2 = sqdist_f32(cx, cy, cz, s2 + (size_t)tid * 3);
    b2 = (((unsigned long long)__float_as_uint(d2)) << 32) | (unsigned)tid;
  }
#pragma unroll
  for (int off = 32; off > 0; off >>= 1) {
    unsigned long long o1 = __shfl_down(b1, off);
    unsigned long long o2 = __shfl_down(b2, off);
    b1 = b1 < o1 ? b1 : o1;
    b2 = b2 < o2 ? b2 : o2;
  }
  if (lane == 0) { sred[wv] = b1; sred[4 + wv] = b2; }
  __syncthreads();
  if (tid == 0) {
    unsigned long long m1 = sred[0], m2 = sred[4];
#pragma unroll
    for (int r = 1; r < 4; ++r) {
      m1 = m1 < sred[r] ? m1 : sred[r];
      m2 = m2 < sred[4 + r] ? m2 : sred[4 + r];
    }
    sn12[0] = (int)(m1 & 0xffffffffu);
    sn12[1] = (int)(m2 & 0xffffffffu);
  }
  __syncthreads();
  int sn1 = sn12[0], sn2 = sn12[1];
  const float* r2 = fm2 + (size_t)bv * 96;
  const float* r5 = fm5 + ((size_t)b * V1N + sn1) * 192;
  const float* r7 = fm7 + ((size_t)b * V2N + sn2) * 256;
  const float* rg = fglob + b * 256;
  const float* roh = onehot + b * 16;
  if (tid < KP1 / 8) {
    int c = tid * 8;
    const float* src = nullptr;
    if (c < 192) {
      int cc = (c < 32) ? c : (c < 96 ? c - 32 : c - 96);
      src = r2 + cc;
    } else if (c < 672) {
      int cc = (c < 320) ? c - 192 : (c < 480 ? c - 320 : c - 480);
      src = r5 + cc;
    } else if (c < 1152) {
      int cc = (c < 896) ? c - 672 : c - 896;
      src = r7 + cc;
    } else if (c < 1408) {
      src = rg + (c - 1152);
    } else if (c < 1424) {
      src = roh + (c - 1408);
    }
    float4 lo = make_float4(0.f, 0.f, 0.f, 0.f), hi = lo;
    if (src) { lo = *(const float4*)src; hi = *(const float4*)(src + 4); }
    bf16x8 o;
    o[0] = (short)f2bf(lo.x); o[1] = (short)f2bf(lo.y);
    o[2] = (short)f2bf(lo.z); o[3] = (short)f2bf(lo.w);
    o[4] = (short)f2bf(hi.x); o[5] = (short)f2bf(hi.y);
    o[6] = (short)f2bf(hi.z); o[7] = (short)f2bf(hi.w);
    *(bf16x8*)(fuse_b + (size_t)bv * KP1 + c) = o;
  }
}

// ---------------------------------------------------------------------------
// bf16 MFMA GEMM — BK=64 + XCD swizzle + XOR-8 chunk swizzle (128² tile).
// Used for GEMM2/GEMM3.
// ---------------------------------------------------------------------------
typedef const __attribute__((address_space(1))) unsigned int gas_u32;
typedef __attribute__((address_space(3))) unsigned int las_u32;

__global__ __launch_bounds__(256) void gemm_mfma_nt(
    const ushort_t* __restrict__ A, const ushort_t* __restrict__ B,
    const float* __restrict__ bias, ushort_t* __restrict__ Cb,
    float* __restrict__ Cf, int K, int ldc, int nvalid, int mode) {
  __shared__ ushort_t As[128 * 64];
  __shared__ ushort_t Bs[128 * 64];
  int tid = threadIdx.x;
  int lane = tid & 63, w = tid >> 6;
  int wm = (w >> 1) * 64, wn = (w & 1) * 64;
  int nb = gridDim.x;
  int flat = blockIdx.x + nb * blockIdx.y;
  int xcd = flat & 7, slot = flat >> 3;
  int nidx = slot % nb;
  int mband = xcd + 8 * (slot / nb);
  int bm = mband * 128, bn = nidx * 128;
  f32x4 acc[4][4];
#pragma unroll
  for (int i = 0; i < 4; ++i)
#pragma unroll
    for (int j = 0; j < 4; ++j) acc[i][j] = (f32x4){0.f, 0.f, 0.f, 0.f};

  const ushort_t* gA[4];
  const ushort_t* gB[4];
  ushort_t* lA[4];
  ushort_t* lB[4];
  int rsub = lane >> 3;                      // row within 8-row DMA group
  int scol = ((lane & 7) ^ rsub) * 8;        // XOR-8 swizzled global chunk
#pragma unroll
  for (int g = 0; g < 4; ++g) {
    int r = w * 32 + g * 8 + rsub;
    gA[g] = A + (size_t)(bm + r) * K + scol;
    gB[g] = B + (size_t)(bn + r) * K + scol;
    lA[g] = As + (w * 32 + g * 8) * 64;
    lB[g] = Bs + (w * 32 + g * 8) * 64;
  }
  int rA = lane & 15, q = lane >> 4;
  int r7 = rA & 7;                            // row&7 for de-swizzle

  for (int k0 = 0; k0 < K; k0 += 64) {
#pragma unroll
    for (int g = 0; g < 4; ++g)
      __builtin_amdgcn_global_load_lds((gas_u32*)(gA[g] + k0), (las_u32*)lA[g],
                                       16, 0, 0);
#pragma unroll
    for (int g = 0; g < 4; ++g)
      __builtin_amdgcn_global_load_lds((gas_u32*)(gB[g] + k0), (las_u32*)lB[g],
                                       16, 0, 0);
    __syncthreads();
#pragma unroll
    for (int s = 0; s < 2; ++s) {
      int pc = ((s * 4 + q) ^ r7) * 8;        // physical chunk offset
      bf16x8 af[4], bfr[4];
#pragma unroll
      for (int i = 0; i < 4; ++i)
        af[i] = *(const bf16x8*)(As + (wm + i * 16 + rA) * 64 + pc);
#pragma unroll
      for (int j = 0; j < 4; ++j)
        bfr[j] = *(const bf16x8*)(Bs + (wn + j * 16 + rA) * 64 + pc);
#pragma unroll
      for (int i = 0; i < 4; ++i)
#pragma unroll
        for (int j = 0; j < 4; ++j)
          acc[i][j] = __builtin_amdgcn_mfma_f32_16x16x32_bf16(af[i], bfr[j],
                                                              acc[i][j], 0, 0, 0);
    }
    __syncthreads();
  }

  int rowq = (lane >> 4) * 4;
  int coll = lane & 15;
#pragma unroll
  for (int i = 0; i < 4; ++i) {
#pragma unroll
    for (int j = 0; j < 4; ++j) {
      int col = bn + wn + j * 16 + coll;
      float bi = bias[col];
#pragma unroll
      for (int r = 0; r < 4; ++r) {
        int row = bm + wm + i * 16 + rowq + r;
        float v = acc[i][j][r] + bi;
        if (mode == 0) {
          Cb[(size_t)row * ldc + col] = f2bf(fmaxf(v, 0.f));
        } else if (col < nvalid) {
          Cf[(size_t)row * ldc + col] = v;
        }
      }
    }
  }
}

// ---------------------------------------------------------------------------
// gemm256: 256×256 tile, 8 waves (2M×4N), BK=64, double-buffered LDS
// (128 KiB). R17: fully barrier-thinned — ONE barrier per tile (the
// tile-top validity barrier). Ledger: (a) MFMA correctness needs only the
// wave's own per-phase lgkmcnt(0); (b) tile-t LDS validity is established
// once at the tile-top barrier (all waves' staging from tile t-1 landed,
// own loads via vmcnt(0)); (c) buffer-reuse safety: every wave's final
// phase lgkmcnt(0) of tile t-1 precedes its arrival at the tile-t top
// barrier, so all buf t-1 reads are drained before tile-t staging (which
// writes buf t-1's space) is issued after that barrier. Barrier count
// uniform (1/tile). R16 (5 barriers) measured 49.1 µs vs R15's 52.0 (9
// barriers); this removes the remaining 4 pre-MFMA phase barriers.
// ---------------------------------------------------------------------------
__global__ __launch_bounds__(512, 2) void gemm256_mfma_nt(
    const ushort_t* __restrict__ A, const ushort_t* __restrict__ B,
    const float* __restrict__ bias, ushort_t* __restrict__ Cb,
    int K, int ldc) {
  __shared__ ushort_t As[2 * 256 * 64];   // 64 KiB
  __shared__ ushort_t Bs[2 * 256 * 64];   // 64 KiB
  int tid = threadIdx.x;
  int lane = tid & 63, w = tid >> 6;
  int wm = (w >> 2) * 128, wn = (w & 3) * 64;

  int flat = blockIdx.x;
  int xcd = flat & 7, slot = flat >> 3;
  int nidx = slot & 3, mband = xcd + 8 * (slot >> 2);
  int bm = mband * 256, bn = nidx * 256;

  f32x4 acc[8][4];
#pragma unroll
  for (int i = 0; i < 8; ++i)
#pragma unroll
    for (int j = 0; j < 4; ++j) acc[i][j] = (f32x4){0.f, 0.f, 0.f, 0.f};

  int rloc = tid >> 3, cch = tid & 7;
  int gc = (cch ^ (rloc & 7)) * 8;
  const ushort_t* gA[4];
  const ushort_t* gB[4];
#pragma unroll
  for (int i = 0; i < 4; ++i) {
    gA[i] = A + (size_t)(bm + i * 64 + rloc) * K + gc;
    gB[i] = B + (size_t)(bn + i * 64 + rloc) * K + gc;
  }
  int lofs = tid * 8;

  int rA = lane & 15, r7 = lane & 7;
  int qlane = lane >> 4;
  int pc0 = (qlane ^ r7) * 8;         // physical chunk col, k-half 0
  int pc1 = ((4 + qlane) ^ r7) * 8;   // physical chunk col, k-half 1

  int NT = K >> 6;

  // prologue: stage tile 0 into buffer 0
#pragma unroll
  for (int i = 0; i < 4; ++i) {
    __builtin_amdgcn_global_load_lds((gas_u32*)gA[i],
                                     (las_u32*)(As + i * 4096 + lofs), 16, 0, 0);
    gA[i] += 64;
  }
#pragma unroll
  for (int i = 0; i < 4; ++i) {
    __builtin_amdgcn_global_load_lds((gas_u32*)gB[i],
                                     (las_u32*)(Bs + i * 4096 + lofs), 16, 0, 0);
    gB[i] += 64;
  }

  for (int t = 0; t < NT; ++t) {
    int doff = (t & 1) * 16384;
    int poff = doff ^ 16384;
    const ushort_t* Ab = As + doff;
    const ushort_t* Bb = Bs + doff;
    bool pf = (t + 1 < NT);

    // tile-validity: own loads landed, then barrier so ALL waves' staged
    // chunks of tile t are visible before any ds_read of it. Also proves
    // all waves drained their buf t-1 reads (per-phase lgkmcnt(0) below).
    asm volatile("s_waitcnt vmcnt(0)" ::: "memory");
    __builtin_amdgcn_sched_barrier(0);
    __builtin_amdgcn_s_barrier();
    __builtin_amdgcn_sched_barrier(0);

#pragma unroll
    for (int q = 0; q < 4; ++q) {
      int band = q >> 1, kh = q & 1;
      int pck = kh ? pc1 : pc0;

      // phase reads issued first: 4 A-band frags + 4 B frags (8 × b128)
      bf16x8 af[4], bfq[4];
#pragma unroll
      for (int fi = 0; fi < 4; ++fi)
        af[fi] = *(const bf16x8*)(Ab + (wm + band * 64 + fi * 16 + rA) * 64 + pck);
#pragma unroll
      for (int fj = 0; fj < 4; ++fj)
        bfq[fj] = *(const bf16x8*)(Bb + (wn + fj * 16 + rA) * 64 + pck);

      // stage 2 chunks of tile t+1 (phases 0,1 -> A halves; 2,3 -> B halves)
      if (pf) {
        if (q < 2) {
          __builtin_amdgcn_global_load_lds(
              (gas_u32*)gA[2 * q],
              (las_u32*)(As + poff + (2 * q) * 4096 + lofs), 16, 0, 0);
          __builtin_amdgcn_global_load_lds(
              (gas_u32*)gA[2 * q + 1],
              (las_u32*)(As + poff + (2 * q + 1) * 4096 + lofs), 16, 0, 0);
          gA[2 * q] += 64;
          gA[2 * q + 1] += 64;
        } else {
          int i = 2 * (q - 2);
          __builtin_amdgcn_global_load_lds(
              (gas_u32*)gB[i],
              (las_u32*)(Bs + poff + i * 4096 + lofs), 16, 0, 0);
          __builtin_amdgcn_global_load_lds(
              (gas_u32*)gB[i + 1],
              (las_u32*)(Bs + poff + (i + 1) * 4096 + lofs), 16, 0, 0);
          gB[i] += 64;
          gB[i + 1] += 64;
        }
      }

      // R17: pre-MFMA phase barrier removed — only own-read drain needed.
      asm volatile("s_waitcnt lgkmcnt(0)" ::: "memory");
      __builtin_amdgcn_sched_barrier(0);

      __builtin_amdgcn_s_setprio(1);
#pragma unroll
      for (int fi = 0; fi < 4; ++fi)
#pragma unroll
        for (int fj = 0; fj < 4; ++fj)
          acc[band * 4 + fi][fj] = __builtin_amdgcn_mfma_f32_16x16x32_bf16(
              af[fi], bfq[fj], acc[band * 4 + fi][fj], 0, 0, 0);
      __builtin_amdgcn_s_setprio(0);
      __builtin_amdgcn_sched_barrier(0);
    }
  }

  int rowq = (lane >> 4) * 4;
  int coll = lane & 15;
  float bi[4];
#pragma unroll
  for (int j = 0; j < 4; ++j) bi[j] = bias[bn + wn + j * 16 + coll];
#pragma unroll
  for (int i = 0; i < 8; ++i) {
#pragma unroll
    for (int j = 0; j < 4; ++j) {
      int col = bn + wn + j * 16 + coll;
#pragma unroll
      for (int r = 0; r < 4; ++r) {
        int row = bm + wm + i * 16 + rowq + r;
        float v = acc[i][j][r] + bi[j];
        Cb[(size_t)row * ldc + col] = f2bf(fmaxf(v, 0.f));
      }
    }
  }
}

// ---------------------------------------------------------------------------
extern "C" void kernel_launch(void* const* d_in, const int* in_sizes, int n_in,
                              void* d_out, int out_size, void* d_ws,
                              size_t ws_size, hipStream_t stream) {
  const float* vertices = (const float*)d_in[0];
  const float* onehot = (const float*)d_in[1];
  const float* d0 = (const float*)d_in[2];
  const float *w[8], *bb[8], *dd[8];
  for (int i = 1; i <= 7; ++i) {
    w[i] = (const float*)d_in[3 * i];
    bb[i] = (const float*)d_in[3 * i + 1];
    dd[i] = (const float*)d_in[3 * i + 2];
  }
  const float* cw1 = (const float*)d_in[24];
  const float* cb1 = (const float*)d_in[25];
  const float* cw2 = (const float*)d_in[26];
  const float* cb2 = (const float*)d_in[27];
  const float* cw3 = (const float*)d_in[28];
  const float* cb3 = (const float*)d_in[29];
  float* out = (float*)d_out;

  char* wsp = (char*)d_ws;
  size_t off = 0;
  auto alloc = [&](size_t bytes) -> void* {
    void* p = wsp + off;
    off += (bytes + 255) & ~(size_t)255;
    return p;
  };
  const int M = BS * V0;  // 16384
  int* rank = (int*)alloc(4608 * 4);
  int* perm1 = (int*)alloc(512 * 4);
  int* perm2 = (int*)alloc(128 * 4);
  int* ni1 = (int*)alloc((size_t)BS * V0 * 32 * 4);
  int* ni2 = (int*)alloc((size_t)BS * V1N * 32 * 4);
  int* ni3 = (int*)alloc((size_t)BS * V2N * 32 * 4);
  float* fm2buf = (float*)alloc((size_t)BS * V0 * 96 * 4);
  float* fm5buf = (float*)alloc((size_t)BS * V1N * 192 * 4);
  float* fm7buf = (float*)alloc((size_t)BS * V2N * 256 * 4);
  float* fbuf = (float*)alloc((size_t)BS * V0 * 64 * 4);
  float* v1 = (float*)alloc((size_t)BS * V1N * 3 * 4);
  float* v2 = (float*)alloc((size_t)BS * V2N * 3 * 4);
  float* fglob = (float*)alloc((size_t)BS * 256 * 4);
  ushort_t* fuse_b = (ushort_t*)alloc((size_t)M * KP1 * 2);
  ushort_t* h1b = (ushort_t*)alloc((size_t)M * 1024 * 2);
  ushort_t* h2b = (ushort_t*)alloc((size_t)M * 512 * 2);
  ushort_t* cw1b = (ushort_t*)alloc((size_t)1024 * KP1 * 2);
  ushort_t* cw2b = (ushort_t*)alloc((size_t)512 * 1024 * 2);
  ushort_t* cw3b = (ushort_t*)alloc((size_t)128 * 512 * 2);
  float* cb3p = (float*)alloc(128 * 4);

  float rr1 = 0.0625f;
  float rr2 = (float)(0.39 * 0.39);
  float rr3 = (float)(0.63 * 0.63);

  // 0: zero rank accumulators (async, stream-ordered; graph-capture-safe)
  hipMemsetAsync(rank, 0, 4608 * 4, stream);
  // 1: weight-prep + qbp1
  misc1_kernel<<<PREP_BLKS + QBP1_BLKS, 256, 0, stream>>>(
      cw1, cw2, cw3, cb3, cw1b, cw2b, cw3b, cb3p, vertices, ni1);
  // 2: scan-split rank (288 partial blocks, hidden) + conv_surface(+linear1)
  misc2_kernel<<<RANK_BLKS + BS * V0 / 8, 256, 0, stream>>>(
      rank, vertices, ni1, d0, w[1], bb[1], fm2buf, fbuf);
  // 2b: perm compose (needs rank; before pool1)
  perm_kernel<<<1, 256, 0, stream>>>(rank, perm1, perm2);
  // 3-4: level-1 convs
  conv_act_kernel<<<BS * V0 / 8, 256, 0, stream>>>(
      vertices, dd[1], ni1, fbuf, fm2buf, V0, 96, 32, w[2], bb[2], fbuf);
  conv_act_kernel<<<BS * V0 / 8, 256, 0, stream>>>(
      vertices, dd[2], ni1, fbuf, fm2buf, V0, 96, 64, nullptr, nullptr, nullptr);
  // 5: pool1 (+linear3)
  pool_kernel<<<BS * V1N / 4, 256, 0, stream>>>(
      vertices, fm2buf, 96, 96, V0, perm1, V1N, rr1, v1, fm5buf, 192,
      w[3], bb[3], fbuf);
  // 6-8: level-2 convs (first fuses qbp2 + linear4)
  conv_act_qbp_kernel<<<BS * V1N / 8, 256, 0, stream>>>(
      v1, V1N, rr2, dd[3], ni2, fbuf, fm5buf, 192, 96, w[4], bb[4], fbuf);
  conv_act_kernel<<<BS * V1N / 8, 256, 0, stream>>>(
      v1, dd[4], ni2, fbuf, fm5buf, V1N, 192, 128, w[5], bb[5], fbuf);
  conv_act_kernel<<<BS * V1N / 8, 256, 0, stream>>>(
      v1, dd[5], ni2, fbuf, fm5buf, V1N, 192, 160, nullptr, nullptr, nullptr);
  // 9: pool2 (+linear6)
  pool_kernel<<<BS * V2N / 4, 256, 0, stream>>>(
      v1, fm5buf, 192, 192, V1N, perm2, V2N, rr2, v2, fm7buf, 256,
      w[6], bb[6], fbuf);
  // 10-11: level-3 convs (first fuses qbp3 + linear7)
  conv_act_qbp_kernel<<<BS * V2N / 8, 256, 0, stream>>>(
      v2, V2N, rr3, dd[6], ni3, fbuf, fm7buf, 256, 192, w[7], bb[7], fbuf);
  conv_act_kernel<<<BS * V2N / 8, 256, 0, stream>>>(
      v2, dd[7], ni3, fbuf, fm7buf, V2N, 256, 224, nullptr, nullptr, nullptr);
  // 12: global max (64 blocks, coalesced)
  gmax_kernel<<<64, 256, 0, stream>>>(fm7buf, fglob);
  // 13: fused nearest + gather + bf16 cast (wave-shuffle argmin)
  fuse_row_kernel<<<M, 256, 0, stream>>>(fm2buf, fm5buf, fm7buf, fglob, onehot,
                                         vertices, v1, v2, fuse_b);
  // 14: MLP layer 1 — 256² 1-barrier/tile 4-phase schedule
  gemm256_mfma_nt<<<(M / 256) * (1024 / 256), 512, 0, stream>>>(
      fuse_b, cw1b, cb1, h1b, KP1, 1024);
  // 15-16: MLP layers 2-3 (128² kernel)
  gemm_mfma_nt<<<dim3(512 / 128, M / 128), 256, 0, stream>>>(
      h1b, cw2b, cb2, h2b, nullptr, 1024, 512, 512, 0);
  gemm_mfma_nt<<<dim3(1, M / 128), 256, 0, stream>>>(
      h2b, cw3b, cb3p, nullptr, out, 512, 50, 50, 1);
}